// Round 6
// baseline (352.061 us; speedup 1.0000x reference)
//
#include <hip/hip_runtime.h>

#define H_IMG 1024
#define W_IMG 1024
#define N_IMG 16
#define C_IMG 3

typedef float f2 __attribute__((ext_vector_type(2)));

// Each block covers 512 consecutive pixels; thread t handles pix0+t and
// pix0+256+t. Every load/store group keeps 64-consecutive-lane coalescing
// (round 3 showed lane-stride>1 blows up FETCH). 12 paired gathers in
// flight per thread -> 2x the MLP of the round-5 kernel at half the waves.
__global__ __launch_bounds__(256) void homography_warp_kernel(
    const float* __restrict__ img,   // [N, 3, H, W]
    const float* __restrict__ homo,  // [N, 3, 3]
    float* __restrict__ out)         // [N, 3, H, W]
{
    const int n    = blockIdx.y;
    const int pixA = blockIdx.x * 512 + threadIdx.x;       // group A pixel
    const int pixB = pixA + 256;                           // group B pixel

    // Block-uniform homography coefficients
    const float* Hm = homo + n * 9;
    const float h00 = Hm[0], h01 = Hm[1], h02 = Hm[2];
    const float h10 = Hm[3], h11 = Hm[4], h12 = Hm[5];
    const float h20 = Hm[6], h21 = Hm[7], h22 = Hm[8];

    const size_t plane = (size_t)H_IMG * W_IMG;
    const size_t base  = (size_t)n * C_IMG * plane;
    const float* p0 = img + base;        // c = 0
    const float* p1 = p0 + plane;        // c = 1
    const float* p2 = p1 + plane;        // c = 2

    // ---- per-pixel setup: offsets + lo/hi pair weights --------------------
    int   oA0, oA1, oB0, oB1;
    float wlA0, whA0, wlA1, whA1, wlB0, whB0, wlB1, whB1;

#pragma unroll
    for (int g = 0; g < 2; ++g) {
        const int pix = g ? pixB : pixA;
        const int h   = pix >> 10;                 // W_IMG == 1024
        const int w   = pix & (W_IMG - 1);

        const float gx = fmaf((float)w, 2.0f / (W_IMG - 1), -1.0f);
        const float gy = fmaf((float)h, 2.0f / (H_IMG - 1), -1.0f);

        const float tx = fmaf(h00, gx, fmaf(h01, gy, h02));
        const float ty = fmaf(h10, gx, fmaf(h11, gy, h12));
        const float tz = fmaf(h20, gx, fmaf(h21, gy, h22));
        const float inv = 1.0f / tz;               // accurate fp32 division
        const float u = tx * inv;
        const float v = ty * inv;

        const float xp = (u + 1.0f) * 0.5f * (float)(W_IMG - 1);
        const float yp = (v + 1.0f) * 0.5f * (float)(H_IMG - 1);

        const float x0f = floorf(xp);
        const float y0f = floorf(yp);
        const float fx = xp - x0f;
        const float fy = yp - y0f;

        const int ix0 = (int)x0f;
        const int iy0 = (int)y0f;
        const int ix1 = ix0 + 1;
        const int iy1 = iy0 + 1;

        const float vx0 = (ix0 >= 0 && ix0 < W_IMG) ? 1.0f : 0.0f;
        const float vx1 = (ix1 >= 0 && ix1 < W_IMG) ? 1.0f : 0.0f;
        const float vy0 = (iy0 >= 0 && iy0 < H_IMG) ? 1.0f : 0.0f;
        const float vy1 = (iy1 >= 0 && iy1 < H_IMG) ? 1.0f : 0.0f;

        const float w00 = (1.0f - fx) * (1.0f - fy) * vx0 * vy0;
        const float w01 = fx * (1.0f - fy) * vx1 * vy0;
        const float w10 = (1.0f - fx) * fy * vx0 * vy1;
        const float w11 = fx * fy * vx1 * vy1;

        // paired-corner load base: x0/x1 adjacent -> one dwordx2 at
        // clamp(ix0, 0, W-2); pre-select lo/hi halves (OOB weight = 0
        // makes the selects exact at edges).
        const int  pbx    = min(max(ix0, 0), W_IMG - 2);
        const bool selhi0 = (ix0 > pbx);
        const bool selhi1 = (ix0 >= 0);

        const float wl0 = (selhi0 ? 0.0f : w00) + (selhi1 ? 0.0f : w01);
        const float wh0 = (selhi0 ? w00 : 0.0f) + (selhi1 ? w01 : 0.0f);
        const float wl1 = (selhi0 ? 0.0f : w10) + (selhi1 ? 0.0f : w11);
        const float wh1 = (selhi0 ? w10 : 0.0f) + (selhi1 ? w11 : 0.0f);

        const int cy0 = min(max(iy0, 0), H_IMG - 1);
        const int cy1 = min(max(iy1, 0), H_IMG - 1);
        const int o0 = cy0 * W_IMG + pbx;
        const int o1 = cy1 * W_IMG + pbx;

        if (g == 0) { oA0 = o0; oA1 = o1; wlA0 = wl0; whA0 = wh0; wlA1 = wl1; whA1 = wh1; }
        else        { oB0 = o0; oB1 = o1; wlB0 = wl0; whB0 = wh0; wlB1 = wl1; whB1 = wh1; }
    }

    // ---- issue all 12 paired gathers before any consumption ---------------
    f2 a0A, b0A, a1A, b1A, a2A, b2A;
    f2 a0B, b0B, a1B, b1B, a2B, b2B;
    __builtin_memcpy(&a0A, p0 + oA0, 8);
    __builtin_memcpy(&b0A, p0 + oA1, 8);
    __builtin_memcpy(&a1A, p1 + oA0, 8);
    __builtin_memcpy(&b1A, p1 + oA1, 8);
    __builtin_memcpy(&a2A, p2 + oA0, 8);
    __builtin_memcpy(&b2A, p2 + oA1, 8);
    __builtin_memcpy(&a0B, p0 + oB0, 8);
    __builtin_memcpy(&b0B, p0 + oB1, 8);
    __builtin_memcpy(&a1B, p1 + oB0, 8);
    __builtin_memcpy(&b1B, p1 + oB1, 8);
    __builtin_memcpy(&a2B, p2 + oB0, 8);
    __builtin_memcpy(&b2B, p2 + oB1, 8);

    const float r0A = wlA0 * a0A.x + whA0 * a0A.y + wlA1 * b0A.x + whA1 * b0A.y;
    const float r1A = wlA0 * a1A.x + whA0 * a1A.y + wlA1 * b1A.x + whA1 * b1A.y;
    const float r2A = wlA0 * a2A.x + whA0 * a2A.y + wlA1 * b2A.x + whA1 * b2A.y;
    const float r0B = wlB0 * a0B.x + whB0 * a0B.y + wlB1 * b0B.x + whB1 * b0B.y;
    const float r1B = wlB0 * a1B.x + whB0 * a1B.y + wlB1 * b1B.x + whB1 * b1B.y;
    const float r2B = wlB0 * a2B.x + whB0 * a2B.y + wlB1 * b2B.x + whB1 * b2B.y;

    out[base + (size_t)pixA]             = r0A;
    out[base + plane + (size_t)pixA]     = r1A;
    out[base + 2 * plane + (size_t)pixA] = r2A;
    out[base + (size_t)pixB]             = r0B;
    out[base + plane + (size_t)pixB]     = r1B;
    out[base + 2 * plane + (size_t)pixB] = r2B;
}

extern "C" void kernel_launch(void* const* d_in, const int* in_sizes, int n_in,
                              void* d_out, int out_size, void* d_ws, size_t ws_size,
                              hipStream_t stream) {
    const float* img  = (const float*)d_in[0];   // patch_src    [16,3,1024,1024]
    const float* homo = (const float*)d_in[1];   // dst_homo_src [16,3,3]
    float* out = (float*)d_out;                  // [16,3,1024,1024] fp32

    dim3 block(256);
    dim3 grid((H_IMG * W_IMG) / 512, N_IMG);
    homography_warp_kernel<<<grid, block, 0, stream>>>(img, homo, out);
}

// Round 7
// 346.617 us; speedup vs baseline: 1.0157x; 1.0157x over previous
//
#include <hip/hip_runtime.h>

#define H_IMG 1024
#define W_IMG 1024
#define N_IMG 16
#define C_IMG 3

typedef float f2 __attribute__((ext_vector_type(2)));

// Vertical 2-px/thread: thread handles (h, w) and (h+1, w). The warp is
// near-identity, so pixel A's y1 image row == pixel B's y0 image row ->
// the row-overlap reuse happens at L1/within-thread instead of relying on
// cross-block L2 timing (round 6's horizontal split blew FETCH up +45%).
// 12 paired dwordx2 gathers in flight per thread, all issued before use.
__global__ __launch_bounds__(256) void homography_warp_kernel(
    const float* __restrict__ img,   // [N, 3, H, W]
    const float* __restrict__ homo,  // [N, 3, 3]
    float* __restrict__ out)         // [N, 3, H, W]
{
    const int n    = blockIdx.y;
    const int bx   = blockIdx.x;          // 2048 tiles/image: 512 row-pairs x 4 col-blocks
    const int bh   = bx >> 2;             // row-pair index 0..511
    const int bw   = bx & 3;              // column block 0..3
    const int col  = bw * 256 + threadIdx.x;
    const int rowA = bh * 2;
    const int pixA = rowA * W_IMG + col;
    const int pixB = pixA + W_IMG;        // next row, same column

    // Block-uniform homography coefficients
    const float* Hm = homo + n * 9;
    const float h00 = Hm[0], h01 = Hm[1], h02 = Hm[2];
    const float h10 = Hm[3], h11 = Hm[4], h12 = Hm[5];
    const float h20 = Hm[6], h21 = Hm[7], h22 = Hm[8];

    // gx is shared by both pixels (same column) -> hoist gx-partials
    const float gx = fmaf((float)col, 2.0f / (W_IMG - 1), -1.0f);
    const float ax = fmaf(h00, gx, h02);
    const float ay = fmaf(h10, gx, h12);
    const float az = fmaf(h20, gx, h22);

    const size_t plane = (size_t)H_IMG * W_IMG;
    const size_t base  = (size_t)n * C_IMG * plane;
    const float* p0 = img + base;        // c = 0
    const float* p1 = p0 + plane;        // c = 1
    const float* p2 = p1 + plane;        // c = 2

    // ---- per-pixel setup: offsets + lo/hi pair weights --------------------
    int   oA0, oA1, oB0, oB1;
    float wlA0, whA0, wlA1, whA1, wlB0, whB0, wlB1, whB1;

#pragma unroll
    for (int g = 0; g < 2; ++g) {
        const float gy = fmaf((float)(rowA + g), 2.0f / (H_IMG - 1), -1.0f);

        const float tx = fmaf(h01, gy, ax);
        const float ty = fmaf(h11, gy, ay);
        const float tz = fmaf(h21, gy, az);
        const float inv = 1.0f / tz;               // accurate fp32 division
        const float u = tx * inv;
        const float v = ty * inv;

        const float xp = (u + 1.0f) * 0.5f * (float)(W_IMG - 1);
        const float yp = (v + 1.0f) * 0.5f * (float)(H_IMG - 1);

        const float x0f = floorf(xp);
        const float y0f = floorf(yp);
        const float fx = xp - x0f;
        const float fy = yp - y0f;

        const int ix0 = (int)x0f;
        const int iy0 = (int)y0f;
        const int ix1 = ix0 + 1;
        const int iy1 = iy0 + 1;

        const float vx0 = (ix0 >= 0 && ix0 < W_IMG) ? 1.0f : 0.0f;
        const float vx1 = (ix1 >= 0 && ix1 < W_IMG) ? 1.0f : 0.0f;
        const float vy0 = (iy0 >= 0 && iy0 < H_IMG) ? 1.0f : 0.0f;
        const float vy1 = (iy1 >= 0 && iy1 < H_IMG) ? 1.0f : 0.0f;

        const float w00 = (1.0f - fx) * (1.0f - fy) * vx0 * vy0;
        const float w01 = fx * (1.0f - fy) * vx1 * vy0;
        const float w10 = (1.0f - fx) * fy * vx0 * vy1;
        const float w11 = fx * fy * vx1 * vy1;

        // paired-corner load base: x0/x1 adjacent -> one dwordx2 at
        // clamp(ix0, 0, W-2); pre-select lo/hi halves (OOB weight = 0
        // makes the selects exact at edges).
        const int  pbx    = min(max(ix0, 0), W_IMG - 2);
        const bool selhi0 = (ix0 > pbx);
        const bool selhi1 = (ix0 >= 0);

        const float wl0 = (selhi0 ? 0.0f : w00) + (selhi1 ? 0.0f : w01);
        const float wh0 = (selhi0 ? w00 : 0.0f) + (selhi1 ? w01 : 0.0f);
        const float wl1 = (selhi0 ? 0.0f : w10) + (selhi1 ? 0.0f : w11);
        const float wh1 = (selhi0 ? w10 : 0.0f) + (selhi1 ? w11 : 0.0f);

        const int cy0 = min(max(iy0, 0), H_IMG - 1);
        const int cy1 = min(max(iy1, 0), H_IMG - 1);
        const int o0 = cy0 * W_IMG + pbx;
        const int o1 = cy1 * W_IMG + pbx;

        if (g == 0) { oA0 = o0; oA1 = o1; wlA0 = wl0; whA0 = wh0; wlA1 = wl1; whA1 = wh1; }
        else        { oB0 = o0; oB1 = o1; wlB0 = wl0; whB0 = wh0; wlB1 = wl1; whB1 = wh1; }
    }

    // ---- issue all 12 paired gathers before any consumption ---------------
    // A's y1-row (oA1) and B's y0-row (oB0) usually hit the same cachelines.
    f2 a0A, b0A, a1A, b1A, a2A, b2A;
    f2 a0B, b0B, a1B, b1B, a2B, b2B;
    __builtin_memcpy(&a0A, p0 + oA0, 8);
    __builtin_memcpy(&b0A, p0 + oA1, 8);
    __builtin_memcpy(&a0B, p0 + oB0, 8);
    __builtin_memcpy(&b0B, p0 + oB1, 8);
    __builtin_memcpy(&a1A, p1 + oA0, 8);
    __builtin_memcpy(&b1A, p1 + oA1, 8);
    __builtin_memcpy(&a1B, p1 + oB0, 8);
    __builtin_memcpy(&b1B, p1 + oB1, 8);
    __builtin_memcpy(&a2A, p2 + oA0, 8);
    __builtin_memcpy(&b2A, p2 + oA1, 8);
    __builtin_memcpy(&a2B, p2 + oB0, 8);
    __builtin_memcpy(&b2B, p2 + oB1, 8);

    const float r0A = wlA0 * a0A.x + whA0 * a0A.y + wlA1 * b0A.x + whA1 * b0A.y;
    const float r1A = wlA0 * a1A.x + whA0 * a1A.y + wlA1 * b1A.x + whA1 * b1A.y;
    const float r2A = wlA0 * a2A.x + whA0 * a2A.y + wlA1 * b2A.x + whA1 * b2A.y;
    const float r0B = wlB0 * a0B.x + whB0 * a0B.y + wlB1 * b0B.x + whB1 * b0B.y;
    const float r1B = wlB0 * a1B.x + whB0 * a1B.y + wlB1 * b1B.x + whB1 * b1B.y;
    const float r2B = wlB0 * a2B.x + whB0 * a2B.y + wlB1 * b2B.x + whB1 * b2B.y;

    out[base + (size_t)pixA]             = r0A;
    out[base + plane + (size_t)pixA]     = r1A;
    out[base + 2 * plane + (size_t)pixA] = r2A;
    out[base + (size_t)pixB]             = r0B;
    out[base + plane + (size_t)pixB]     = r1B;
    out[base + 2 * plane + (size_t)pixB] = r2B;
}

extern "C" void kernel_launch(void* const* d_in, const int* in_sizes, int n_in,
                              void* d_out, int out_size, void* d_ws, size_t ws_size,
                              hipStream_t stream) {
    const float* img  = (const float*)d_in[0];   // patch_src    [16,3,1024,1024]
    const float* homo = (const float*)d_in[1];   // dst_homo_src [16,3,3]
    float* out = (float*)d_out;                  // [16,3,1024,1024] fp32

    dim3 block(256);
    dim3 grid((H_IMG * W_IMG) / 512, N_IMG);   // 2048 tiles/image (2 rows x 256 cols each)
    homography_warp_kernel<<<grid, block, 0, stream>>>(img, homo, out);
}